// Round 4
// baseline (1014.590 us; speedup 1.0000x reference)
//
#include <hip/hip_runtime.h>

#define B_    2
#define COND_ 4
#define C_    128
#define S_    32768      // 32*32*32
#define VT_   16         // voxels per block tile (1 wave)
#define LDT_  136        // padded LDS row stride in halves: 128 + 8

typedef __attribute__((ext_vector_type(8))) _Float16 f16x8;
typedef __attribute__((ext_vector_type(4))) _Float16 f16x4;
typedef __attribute__((ext_vector_type(4))) float    f32x4;

#define MFMA16(a,b,c) __builtin_amdgcn_mfma_f32_16x16x32_f16((a),(b),(c),0,0,0)

// Stage one [128 ch][16 vox] fp32 global tile into LDS as fp16 hi+lo pair,
// layout [16 vox][LDT_ ch]. 64 threads: t&3 = voxel-quad, t>>2 = 8-ch group.
__device__ __forceinline__ void stage_tile_hl(const float* __restrict__ g,
                                              _Float16* __restrict__ Th,
                                              _Float16* __restrict__ Tl, int t) {
  const int vq  = t & 3;
  const int ch0 = (t >> 2) * 8;
  f32x4 f[8];
  #pragma unroll
  for (int r = 0; r < 8; ++r)
    f[r] = *(const f32x4*)(g + (size_t)(ch0 + r) * S_ + vq * 4);
  #pragma unroll
  for (int i = 0; i < 4; ++i) {
    f16x8 hh, ll;
    #pragma unroll
    for (int r = 0; r < 8; ++r) {
      float x = f[r][i];
      _Float16 h = (_Float16)x;
      hh[r] = h;
      ll[r] = (_Float16)(x - (float)h);
    }
    const int v = vq * 4 + i;
    *(f16x8*)&Th[v * LDT_ + ch0] = hh;
    *(f16x8*)&Tl[v * LDT_ + ch0] = ll;
  }
}

// Convert the four 128x128 fp32 weight matrices to fp16 hi + lo.
__global__ void wcvt_kernel(const float* __restrict__ wq, const float* __restrict__ wk,
                            const float* __restrict__ wv, const float* __restrict__ wo,
                            _Float16* __restrict__ Wh, _Float16* __restrict__ Wl) {
  int i = blockIdx.x * 256 + threadIdx.x;   // grid 64 -> 16384 threads
  const float* src[4] = {wq, wk, wv, wo};
  #pragma unroll
  for (int m = 0; m < 4; ++m) {
    float x = src[m][i];
    _Float16 h = (_Float16)x;
    Wh[m * 16384 + i] = h;
    Wl[m * 16384 + i] = (_Float16)(x - (float)h);
  }
}

// One wave per 16-voxel tile. MFMA 16x16x32 f16, hi/lo split precision:
// W·x ~= Wh·xh + Wh·xl + Wl·xh  (error ~2^-21 per product, fp32-grade).
// A = W (M=out_ch, lane&15 = row), B = X ([vox][cin] LDS, lane&15 = col),
// C/D: col=lane&15 (vox), row=(lane>>4)*4+reg (ch). Head m == GN group m.
__global__ __launch_bounds__(64) void attn_kernel(
    const float* __restrict__ skip, const float* __restrict__ dec,
    const _Float16* __restrict__ Wh, const _Float16* __restrict__ Wl,
    const float* __restrict__ bq, const float* __restrict__ bk,
    const float* __restrict__ bv, const float* __restrict__ bo,
    _Float16* __restrict__ ws_attn, float* __restrict__ stats) {
  __shared__ _Float16 skh[COND_][VT_ * LDT_];
  __shared__ _Float16 skl[COND_][VT_ * LDT_];
  __shared__ _Float16 sxh[VT_ * LDT_];
  __shared__ _Float16 sxl[VT_ * LDT_];
  __shared__ _Float16 so[VT_ * LDT_];

  const int l   = threadIdx.x;
  const int b   = blockIdx.y;
  const int s0  = blockIdx.x * VT_;
  const int row = l & 15;                 // MFMA A-row / B-col / D-col
  const int kh  = l >> 4;                 // 0..3
  const int vox = row;                    // voxel within 16-tile

  stage_tile_hl(dec + (size_t)b * C_ * S_ + s0, sxh, sxl, l);
  #pragma unroll
  for (int c = 0; c < COND_; ++c)
    stage_tile_hl(skip + ((size_t)(b * COND_ + c)) * C_ * S_ + s0, skh[c], skl[c], l);
  __syncthreads();

  // ---------------- Q projection (hi/lo) ----------------
  f32x4 q[8];
  f16x8 bxh[4], bxl[4];
  #pragma unroll
  for (int ks = 0; ks < 4; ++ks) {
    bxh[ks] = *(const f16x8*)&sxh[vox * LDT_ + ks * 32 + kh * 8];
    bxl[ks] = *(const f16x8*)&sxl[vox * LDT_ + ks * 32 + kh * 8];
  }
  #pragma unroll
  for (int m = 0; m < 8; ++m) {
    f16x8 ah[4], al[4];
    #pragma unroll
    for (int ks = 0; ks < 4; ++ks) {
      const size_t off = (size_t)(m * 16 + row) * 128 + ks * 32 + kh * 8;
      ah[ks] = *(const f16x8*)(Wh + off);
      al[ks] = *(const f16x8*)(Wl + off);
    }
    f32x4 acc = *(const f32x4*)(bq + m * 16 + kh * 4);
    #pragma unroll
    for (int ks = 0; ks < 4; ++ks) {
      acc = MFMA16(al[ks], bxh[ks], acc);
      acc = MFMA16(ah[ks], bxl[ks], acc);
      acc = MFMA16(ah[ks], bxh[ks], acc);
    }
    q[m] = acc;
  }

  // ---------------- K projection + scores (hi/lo) ----------------
  float sc[8][4];
  #pragma unroll
  for (int m = 0; m < 8; ++m) {
    f16x8 ah[4], al[4];
    #pragma unroll
    for (int ks = 0; ks < 4; ++ks) {
      const size_t off = 16384 + (size_t)(m * 16 + row) * 128 + ks * 32 + kh * 8;
      ah[ks] = *(const f16x8*)(Wh + off);
      al[ks] = *(const f16x8*)(Wl + off);
    }
    #pragma unroll
    for (int c = 0; c < COND_; ++c) {
      f16x8 bh[4], bl[4];
      #pragma unroll
      for (int ks = 0; ks < 4; ++ks) {
        bh[ks] = *(const f16x8*)&skh[c][vox * LDT_ + ks * 32 + kh * 8];
        bl[ks] = *(const f16x8*)&skl[c][vox * LDT_ + ks * 32 + kh * 8];
      }
      f32x4 acc = *(const f32x4*)(bk + m * 16 + kh * 4);
      #pragma unroll
      for (int ks = 0; ks < 4; ++ks) {
        acc = MFMA16(al[ks], bh[ks], acc);
        acc = MFMA16(ah[ks], bl[ks], acc);
        acc = MFMA16(ah[ks], bh[ks], acc);
      }
      float p = q[m].x * acc.x + q[m].y * acc.y + q[m].z * acc.z + q[m].w * acc.w;
      p += __shfl_xor(p, 16);
      p += __shfl_xor(p, 32);   // all lanes: full 16-ch dot for (vox, head m)
      sc[m][c] = p;
    }
  }

  // ---------------- softmax over cond (scale 1/sqrt(16) = 0.25) ----------------
  float attw[8][4];
  #pragma unroll
  for (int m = 0; m < 8; ++m) {
    float t0 = sc[m][0] * 0.25f, t1 = sc[m][1] * 0.25f;
    float t2 = sc[m][2] * 0.25f, t3 = sc[m][3] * 0.25f;
    float mx = fmaxf(fmaxf(t0, t1), fmaxf(t2, t3));
    float e0 = expf(t0 - mx), e1 = expf(t1 - mx);
    float e2 = expf(t2 - mx), e3 = expf(t3 - mx);
    float inv = 1.0f / (e0 + e1 + e2 + e3);
    attw[m][0] = e0 * inv; attw[m][1] = e1 * inv;
    attw[m][2] = e2 * inv; attw[m][3] = e3 * inv;
  }

  // ---------------- V projection (hi/lo) + weighted accumulation ----------------
  f32x4 o[8];
  #pragma unroll
  for (int m = 0; m < 8; ++m) o[m] = *(const f32x4*)(bv + m * 16 + kh * 4);
  #pragma unroll
  for (int m = 0; m < 8; ++m) {
    f16x8 ah[4], al[4];
    #pragma unroll
    for (int ks = 0; ks < 4; ++ks) {
      const size_t off = 32768 + (size_t)(m * 16 + row) * 128 + ks * 32 + kh * 8;
      ah[ks] = *(const f16x8*)(Wh + off);
      al[ks] = *(const f16x8*)(Wl + off);
    }
    #pragma unroll
    for (int c = 0; c < COND_; ++c) {
      f16x8 bh[4], bl[4];
      #pragma unroll
      for (int ks = 0; ks < 4; ++ks) {
        bh[ks] = *(const f16x8*)&skh[c][vox * LDT_ + ks * 32 + kh * 8];
        bl[ks] = *(const f16x8*)&skl[c][vox * LDT_ + ks * 32 + kh * 8];
      }
      f32x4 acc = {0.f, 0.f, 0.f, 0.f};
      #pragma unroll
      for (int ks = 0; ks < 4; ++ks) {
        acc = MFMA16(al[ks], bh[ks], acc);
        acc = MFMA16(ah[ks], bl[ks], acc);
        acc = MFMA16(ah[ks], bh[ks], acc);
      }
      const float w = attw[m][c];
      o[m].x += w * acc.x; o[m].y += w * acc.y;
      o[m].z += w * acc.z; o[m].w += w * acc.w;
    }
  }

  // ---------------- stage o_pre to LDS ([vox][ch], padded, fp16) ----------------
  #pragma unroll
  for (int m = 0; m < 8; ++m) {
    f16x4 h;
    h[0] = (_Float16)o[m].x; h[1] = (_Float16)o[m].y;
    h[2] = (_Float16)o[m].z; h[3] = (_Float16)o[m].w;
    *(f16x4*)&so[vox * LDT_ + m * 16 + kh * 4] = h;
  }
  __syncthreads();

  // ------- out projection (Wo hi/lo, o_pre single) + residual + GN stats -------
  f16x8 b8[4];
  #pragma unroll
  for (int ks = 0; ks < 4; ++ks)
    b8[ks] = *(const f16x8*)&so[vox * LDT_ + ks * 32 + kh * 8];

  float gsm[8], gsq[8];
  const float* dbase = dec + (size_t)b * C_ * S_ + s0 + vox;
  _Float16* obase = ws_attn + (size_t)b * C_ * S_ + s0 + vox;
  #pragma unroll
  for (int m = 0; m < 8; ++m) {
    f16x8 ah[4], al[4];
    #pragma unroll
    for (int ks = 0; ks < 4; ++ks) {
      const size_t off = 49152 + (size_t)(m * 16 + row) * 128 + ks * 32 + kh * 8;
      ah[ks] = *(const f16x8*)(Wh + off);
      al[ks] = *(const f16x8*)(Wl + off);
    }
    f32x4 acc = *(const f32x4*)(bo + m * 16 + kh * 4);
    #pragma unroll
    for (int ks = 0; ks < 4; ++ks) {
      acc = MFMA16(al[ks], b8[ks], acc);
      acc = MFMA16(ah[ks], b8[ks], acc);
    }
    const int ch = m * 16 + kh * 4;
    acc.x += dbase[(size_t)(ch + 0) * S_];
    acc.y += dbase[(size_t)(ch + 1) * S_];
    acc.z += dbase[(size_t)(ch + 2) * S_];
    acc.w += dbase[(size_t)(ch + 3) * S_];
    _Float16 h0 = (_Float16)acc.x, h1 = (_Float16)acc.y;
    _Float16 h2 = (_Float16)acc.z, h3 = (_Float16)acc.w;
    obase[(size_t)(ch + 0) * S_] = h0;
    obase[(size_t)(ch + 1) * S_] = h1;
    obase[(size_t)(ch + 2) * S_] = h2;
    obase[(size_t)(ch + 3) * S_] = h3;
    // stats from the exact values gn_kernel will read back
    float f0 = (float)h0, f1 = (float)h1, f2 = (float)h2, f3 = (float)h3;
    gsm[m] = f0 + f1 + f2 + f3;
    gsq[m] = f0 * f0 + f1 * f1 + f2 * f2 + f3 * f3;
  }

  #pragma unroll
  for (int m = 0; m < 8; ++m) {
    float s1 = gsm[m], s2 = gsq[m];
    #pragma unroll
    for (int off = 32; off >= 1; off >>= 1) {
      s1 += __shfl_xor(s1, off);
      s2 += __shfl_xor(s2, off);
    }
    gsm[m] = s1; gsq[m] = s2;
  }
  if (l == 0) {
    #pragma unroll
    for (int m = 0; m < 8; ++m) {
      atomicAdd(&stats[(b * 8 + m) * 2 + 0], gsm[m]);
      atomicAdd(&stats[(b * 8 + m) * 2 + 1], gsq[m]);
    }
  }
}

// GroupNorm apply: read fp16 ws, write fp32 out.
__global__ void gn_kernel(const _Float16* __restrict__ src, const float* __restrict__ stats,
                          const float* __restrict__ gamma, const float* __restrict__ beta,
                          float* __restrict__ out) {
  const int n8 = B_ * C_ * S_ / 8;
  const float inv_n = 1.0f / (16.0f * S_);
  for (int i = blockIdx.x * blockDim.x + threadIdx.x; i < n8; i += gridDim.x * blockDim.x) {
    int e0 = i << 3;
    int bc = e0 >> 15;                // element / S
    int c = bc & 127, b = bc >> 7;
    int gi = (b * 8 + (c >> 4)) * 2;
    float mu  = stats[gi] * inv_n;
    float var = stats[gi + 1] * inv_n - mu * mu;
    float rs  = rsqrtf(var + 1e-5f);
    float ga  = gamma[c] * rs;
    float be  = beta[c] - mu * ga;
    f16x8 v = *(const f16x8*)(src + e0);
    float4 o0, o1;
    o0.x = (float)v[0] * ga + be; o0.y = (float)v[1] * ga + be;
    o0.z = (float)v[2] * ga + be; o0.w = (float)v[3] * ga + be;
    o1.x = (float)v[4] * ga + be; o1.y = (float)v[5] * ga + be;
    o1.z = (float)v[6] * ga + be; o1.w = (float)v[7] * ga + be;
    *(float4*)(out + e0)     = o0;
    *(float4*)(out + e0 + 4) = o1;
  }
}

extern "C" void kernel_launch(void* const* d_in, const int* in_sizes, int n_in,
                              void* d_out, int out_size, void* d_ws, size_t ws_size,
                              hipStream_t stream) {
  const float* skip  = (const float*)d_in[0];
  const float* dec   = (const float*)d_in[1];
  const float* wq    = (const float*)d_in[2];
  const float* wk    = (const float*)d_in[3];
  const float* wv    = (const float*)d_in[4];
  const float* bq    = (const float*)d_in[5];
  const float* bk    = (const float*)d_in[6];
  const float* bv    = (const float*)d_in[7];
  const float* wo    = (const float*)d_in[8];
  const float* bo    = (const float*)d_in[9];
  const float* gamma = (const float*)d_in[10];
  const float* beta  = (const float*)d_in[11];

  _Float16* Wh    = (_Float16*)d_ws;                            // 128 KB fp16 weights (hi)
  _Float16* Wl    = (_Float16*)((char*)d_ws + 131072);          // 128 KB fp16 weights (lo)
  float*    stats = (float*)((char*)d_ws + 262144);             // 32 floats
  _Float16* ws_at = (_Float16*)((char*)d_ws + 262272);          // 16 MB fp16 attn out

  hipMemsetAsync(stats, 0, 32 * sizeof(float), stream);
  wcvt_kernel<<<64, 256, 0, stream>>>(wq, wk, wv, wo, Wh, Wl);
  attn_kernel<<<dim3(S_ / VT_, B_), 64, 0, stream>>>(skip, dec, Wh, Wl, bq, bk, bv, bo,
                                                     ws_at, stats);
  gn_kernel<<<2048, 256, 0, stream>>>(ws_at, stats, gamma, beta, (float*)d_out);
}

// Round 6
// 639.384 us; speedup vs baseline: 1.5868x; 1.5868x over previous
//
#include <hip/hip_runtime.h>

#define B_     2
#define COND_  4
#define C_     128
#define S_     32768     // 32*32*32
#define LDF_   132       // fp32 LDS row stride in floats: 128 + 4 (bank spread)
#define NSLOT_ 16        // GN-stats atomic slots

typedef __attribute__((ext_vector_type(8))) _Float16 f16x8;
typedef __attribute__((ext_vector_type(4))) float    f32x4;

#define MFMA16(a,b,c) __builtin_amdgcn_mfma_f32_16x16x32_f16((a),(b),(c),0,0,0)

// Convert the four 128x128 fp32 weight matrices to fp16 hi + lo.
__global__ void wcvt_kernel(const float* __restrict__ wq, const float* __restrict__ wk,
                            const float* __restrict__ wv, const float* __restrict__ wo,
                            _Float16* __restrict__ Wh, _Float16* __restrict__ Wl) {
  int i = blockIdx.x * 256 + threadIdx.x;   // grid 64 -> 16384 threads
  const float* src[4] = {wq, wk, wv, wo};
  #pragma unroll
  for (int m = 0; m < 4; ++m) {
    float x = src[m][i];
    _Float16 h = (_Float16)x;
    Wh[m * 16384 + i] = h;
    Wl[m * 16384 + i] = (_Float16)(x - (float)h);
  }
}

// Load one MFMA B-fragment (8 ch) from an fp32 LDS tile and split hi/lo in-register.
// Bit-identical to r4's precomputed hi/lo fp16 tiles (same rounding sequence).
#define LDFRAG_HL(T, ks, BH, BL)                                              \
  {                                                                           \
    const float* p_ = &(T)[vox * LDF_ + (ks) * 32 + kh * 8];                  \
    f32x4 u0 = *(const f32x4*)p_;                                             \
    f32x4 u1 = *(const f32x4*)(p_ + 4);                                       \
    _Pragma("unroll")                                                         \
    for (int j = 0; j < 4; ++j) {                                             \
      _Float16 h0 = (_Float16)u0[j];                                          \
      (BH)[j] = h0; (BL)[j] = (_Float16)(u0[j] - (float)h0);                  \
      _Float16 h1 = (_Float16)u1[j];                                          \
      (BH)[4 + j] = h1; (BL)[4 + j] = (_Float16)(u1[j] - (float)h1);          \
    }                                                                         \
  }

// One wave per 16-voxel tile. MFMA 16x16x32 f16, hi/lo split precision:
// W·x ~= Wl·xh + Wh·xl + Wh·xh. Online (max-free) softmax over COND folds
// K-proj and V-proj into one cond loop with a single fp32 LDS skip buffer.
// A = W (lane&15 = out-ch row), B = X ([vox][cin] LDS, lane&15 = vox col),
// C/D: col=lane&15 (vox), row=(lane>>4)*4+reg (ch). Head m == GN group m.
__global__ __launch_bounds__(64) void attn_kernel(
    const float* __restrict__ skip, const float* __restrict__ dec,
    const _Float16* __restrict__ Wh, const _Float16* __restrict__ Wl,
    const float* __restrict__ bq, const float* __restrict__ bk,
    const float* __restrict__ bv, const float* __restrict__ bo,
    _Float16* __restrict__ ws_attn, float* __restrict__ stats) {
  __shared__ float sx[16 * LDF_];   // dec tile (fp32, also exact residual source)
  __shared__ float sy[16 * LDF_];   // skip tile (per cond) / o_pre staging

  const int l   = threadIdx.x;
  const int b   = blockIdx.y;
  const int s0  = blockIdx.x * 16;
  const int row = l & 15;           // MFMA A-row / B-col / D-col
  const int kh  = l >> 4;           // 0..3
  const int vox = row;

  const int vq  = l & 3;            // staging: voxel-quad
  const int ch0 = (l >> 2) * 8;     // staging: 8-channel group

  // ---- stage dec tile: [128 ch][16 vox] global -> [16 vox][LDF_] LDS fp32 ----
  {
    const float* g = dec + (size_t)b * C_ * S_ + s0;
    f32x4 f[8];
    #pragma unroll
    for (int r = 0; r < 8; ++r)
      f[r] = *(const f32x4*)(g + (size_t)(ch0 + r) * S_ + vq * 4);
    #pragma unroll
    for (int i = 0; i < 4; ++i) {
      f32x4 t0 = {f[0][i], f[1][i], f[2][i], f[3][i]};
      f32x4 t1 = {f[4][i], f[5][i], f[6][i], f[7][i]};
      *(f32x4*)&sx[(vq * 4 + i) * LDF_ + ch0]     = t0;
      *(f32x4*)&sx[(vq * 4 + i) * LDF_ + ch0 + 4] = t1;
    }
  }
  __syncthreads();

  // ---------------- Q projection (hi/lo) ----------------
  f32x4 q[8];
  {
    f16x8 bxh[4], bxl[4];
    #pragma unroll
    for (int ks = 0; ks < 4; ++ks) LDFRAG_HL(sx, ks, bxh[ks], bxl[ks]);
    #pragma unroll
    for (int m = 0; m < 8; ++m) {
      f16x8 ah[4], al[4];
      #pragma unroll
      for (int ks = 0; ks < 4; ++ks) {
        const size_t off = (size_t)(m * 16 + row) * 128 + ks * 32 + kh * 8;
        ah[ks] = *(const f16x8*)(Wh + off);
        al[ks] = *(const f16x8*)(Wl + off);
      }
      f32x4 acc = *(const f32x4*)(bq + m * 16 + kh * 4);
      #pragma unroll
      for (int ks = 0; ks < 4; ++ks) {
        acc = MFMA16(al[ks], bxh[ks], acc);
        acc = MFMA16(ah[ks], bxl[ks], acc);
        acc = MFMA16(ah[ks], bxh[ks], acc);
      }
      q[m] = acc;
    }
  }

  // ------- cond loop: stage skip[c]; K-proj -> score -> e; V-proj -> o += e*v -------
  f32x4 o[8];
  float lsum[8];
  #pragma unroll
  for (int m = 0; m < 8; ++m) { o[m] = {0.f, 0.f, 0.f, 0.f}; lsum[m] = 0.f; }

  for (int c = 0; c < COND_; ++c) {
    __syncthreads();   // protect sy overwrite vs previous iteration reads
    {
      const float* g = skip + ((size_t)(b * COND_ + c)) * C_ * S_ + s0;
      f32x4 f[8];
      #pragma unroll
      for (int r = 0; r < 8; ++r)
        f[r] = *(const f32x4*)(g + (size_t)(ch0 + r) * S_ + vq * 4);
      #pragma unroll
      for (int i = 0; i < 4; ++i) {
        f32x4 t0 = {f[0][i], f[1][i], f[2][i], f[3][i]};
        f32x4 t1 = {f[4][i], f[5][i], f[6][i], f[7][i]};
        *(f32x4*)&sy[(vq * 4 + i) * LDF_ + ch0]     = t0;
        *(f32x4*)&sy[(vq * 4 + i) * LDF_ + ch0 + 4] = t1;
      }
    }
    __syncthreads();

    f16x8 byh[4], byl[4];
    #pragma unroll
    for (int ks = 0; ks < 4; ++ks) LDFRAG_HL(sy, ks, byh[ks], byl[ks]);

    #pragma unroll
    for (int m = 0; m < 8; ++m) {
      // K projection
      f16x8 ah[4], al[4];
      #pragma unroll
      for (int ks = 0; ks < 4; ++ks) {
        const size_t off = 16384 + (size_t)(m * 16 + row) * 128 + ks * 32 + kh * 8;
        ah[ks] = *(const f16x8*)(Wh + off);
        al[ks] = *(const f16x8*)(Wl + off);
      }
      f32x4 acck = *(const f32x4*)(bk + m * 16 + kh * 4);
      #pragma unroll
      for (int ks = 0; ks < 4; ++ks) {
        acck = MFMA16(al[ks], byh[ks], acck);
        acck = MFMA16(ah[ks], byl[ks], acck);
        acck = MFMA16(ah[ks], byh[ks], acck);
      }
      float p = q[m].x * acck.x + q[m].y * acck.y + q[m].z * acck.z + q[m].w * acck.w;
      p += __shfl_xor(p, 16);
      p += __shfl_xor(p, 32);      // full 16-ch dot for (vox, head m), all lanes
      float e = expf(p * 0.25f);   // max-free: |p/4| << 88, f32-safe
      lsum[m] += e;

      // V projection (reuses byh/byl)
      #pragma unroll
      for (int ks = 0; ks < 4; ++ks) {
        const size_t off = 32768 + (size_t)(m * 16 + row) * 128 + ks * 32 + kh * 8;
        ah[ks] = *(const f16x8*)(Wh + off);
        al[ks] = *(const f16x8*)(Wl + off);
      }
      f32x4 accv = {0.f, 0.f, 0.f, 0.f};
      #pragma unroll
      for (int ks = 0; ks < 4; ++ks) {
        accv = MFMA16(al[ks], byh[ks], accv);
        accv = MFMA16(ah[ks], byl[ks], accv);
        accv = MFMA16(ah[ks], byh[ks], accv);
      }
      o[m].x += e * accv.x; o[m].y += e * accv.y;
      o[m].z += e * accv.z; o[m].w += e * accv.w;
    }
  }

  // ---- normalize + bias (sum_c attw = 1 => bv passes through) ----
  #pragma unroll
  for (int m = 0; m < 8; ++m) {
    float inv = 1.0f / lsum[m];
    f32x4 bb = *(const f32x4*)(bv + m * 16 + kh * 4);
    o[m].x = o[m].x * inv + bb.x;
    o[m].y = o[m].y * inv + bb.y;
    o[m].z = o[m].z * inv + bb.z;
    o[m].w = o[m].w * inv + bb.w;
  }

  // ---- stage o_pre to LDS (fp32, reuse sy) ----
  __syncthreads();
  #pragma unroll
  for (int m = 0; m < 8; ++m)
    *(f32x4*)&sy[vox * LDF_ + m * 16 + kh * 4] = o[m];
  __syncthreads();

  // ------- out projection (Wo hi/lo, o_pre single fp16) + residual + GN stats -------
  f16x8 b8[4];
  #pragma unroll
  for (int ks = 0; ks < 4; ++ks) {
    const float* p_ = &sy[vox * LDF_ + ks * 32 + kh * 8];
    f32x4 u0 = *(const f32x4*)p_;
    f32x4 u1 = *(const f32x4*)(p_ + 4);
    #pragma unroll
    for (int j = 0; j < 4; ++j) {
      b8[ks][j]     = (_Float16)u0[j];
      b8[ks][4 + j] = (_Float16)u1[j];
    }
  }

  float gsm[8], gsq[8];
  _Float16* obase = ws_attn + (size_t)b * C_ * S_ + s0 + vox;
  #pragma unroll
  for (int m = 0; m < 8; ++m) {
    f16x8 ah[4], al[4];
    #pragma unroll
    for (int ks = 0; ks < 4; ++ks) {
      const size_t off = 49152 + (size_t)(m * 16 + row) * 128 + ks * 32 + kh * 8;
      ah[ks] = *(const f16x8*)(Wh + off);
      al[ks] = *(const f16x8*)(Wl + off);
    }
    f32x4 acc = *(const f32x4*)(bo + m * 16 + kh * 4);
    #pragma unroll
    for (int ks = 0; ks < 4; ++ks) {
      acc = MFMA16(al[ks], b8[ks], acc);
      acc = MFMA16(ah[ks], b8[ks], acc);
    }
    const int ch = m * 16 + kh * 4;
    // residual: exact fp32 dec values from LDS (same bits as global)
    f32x4 rd = *(const f32x4*)&sx[vox * LDF_ + ch];
    acc.x += rd.x; acc.y += rd.y; acc.z += rd.z; acc.w += rd.w;
    _Float16 h0 = (_Float16)acc.x, h1 = (_Float16)acc.y;
    _Float16 h2 = (_Float16)acc.z, h3 = (_Float16)acc.w;
    obase[(size_t)(ch + 0) * S_] = h0;
    obase[(size_t)(ch + 1) * S_] = h1;
    obase[(size_t)(ch + 2) * S_] = h2;
    obase[(size_t)(ch + 3) * S_] = h3;
    float f0 = (float)h0, f1 = (float)h1, f2 = (float)h2, f3 = (float)h3;
    gsm[m] = f0 + f1 + f2 + f3;
    gsq[m] = f0 * f0 + f1 * f1 + f2 * f2 + f3 * f3;
  }

  #pragma unroll
  for (int m = 0; m < 8; ++m) {
    float s1 = gsm[m], s2 = gsq[m];
    #pragma unroll
    for (int off = 32; off >= 1; off >>= 1) {
      s1 += __shfl_xor(s1, off);
      s2 += __shfl_xor(s2, off);
    }
    gsm[m] = s1; gsq[m] = s2;
  }
  if (l == 0) {
    const int slot = blockIdx.x & (NSLOT_ - 1);
    #pragma unroll
    for (int m = 0; m < 8; ++m) {
      atomicAdd(&stats[((b * 8 + m) * 2 + 0) * NSLOT_ + slot], gsm[m]);
      atomicAdd(&stats[((b * 8 + m) * 2 + 1) * NSLOT_ + slot], gsq[m]);
    }
  }
}

// GroupNorm apply: slot-summed stats -> per-(b,c) scale/bias in LDS, then
// read fp16 ws, write fp32 out.
__global__ void gn_kernel(const _Float16* __restrict__ src, const float* __restrict__ stats,
                          const float* __restrict__ gamma, const float* __restrict__ beta,
                          float* __restrict__ out) {
  __shared__ float ga_s[256], be_s[256];
  const float inv_n = 1.0f / (16.0f * S_);
  {
    int t = threadIdx.x;               // blockDim == 256
    int bb = t >> 7, c = t & 127, g = c >> 4;
    int base = ((bb * 8 + g) * 2) * NSLOT_;
    float s1 = 0.f, s2 = 0.f;
    #pragma unroll
    for (int k = 0; k < NSLOT_; ++k) {
      s1 += stats[base + k];
      s2 += stats[base + NSLOT_ + k];
    }
    float mu  = s1 * inv_n;
    float var = s2 * inv_n - mu * mu;
    float rs  = rsqrtf(var + 1e-5f);
    float ga  = gamma[c] * rs;
    ga_s[t] = ga;
    be_s[t] = beta[c] - mu * ga;
  }
  __syncthreads();

  const int n8 = B_ * C_ * S_ / 8;
  for (int i = blockIdx.x * blockDim.x + threadIdx.x; i < n8; i += gridDim.x * blockDim.x) {
    int e0 = i << 3;
    int bc = e0 >> 15;                 // b*128 + c
    float ga = ga_s[bc];
    float be = be_s[bc];
    f16x8 v = *(const f16x8*)(src + e0);
    float4 o0, o1;
    o0.x = (float)v[0] * ga + be; o0.y = (float)v[1] * ga + be;
    o0.z = (float)v[2] * ga + be; o0.w = (float)v[3] * ga + be;
    o1.x = (float)v[4] * ga + be; o1.y = (float)v[5] * ga + be;
    o1.z = (float)v[6] * ga + be; o1.w = (float)v[7] * ga + be;
    *(float4*)(out + e0)     = o0;
    *(float4*)(out + e0 + 4) = o1;
  }
}

extern "C" void kernel_launch(void* const* d_in, const int* in_sizes, int n_in,
                              void* d_out, int out_size, void* d_ws, size_t ws_size,
                              hipStream_t stream) {
  const float* skip  = (const float*)d_in[0];
  const float* dec   = (const float*)d_in[1];
  const float* wq    = (const float*)d_in[2];
  const float* wk    = (const float*)d_in[3];
  const float* wv    = (const float*)d_in[4];
  const float* bq    = (const float*)d_in[5];
  const float* bk    = (const float*)d_in[6];
  const float* bv    = (const float*)d_in[7];
  const float* wo    = (const float*)d_in[8];
  const float* bo    = (const float*)d_in[9];
  const float* gamma = (const float*)d_in[10];
  const float* beta  = (const float*)d_in[11];

  _Float16* Wh    = (_Float16*)d_ws;                            // 128 KB fp16 weights (hi)
  _Float16* Wl    = (_Float16*)((char*)d_ws + 131072);          // 128 KB fp16 weights (lo)
  float*    stats = (float*)((char*)d_ws + 262144);             // 512 floats (16 slots)
  _Float16* ws_at = (_Float16*)((char*)d_ws + 264192);          // 16 MB fp16 attn out

  hipMemsetAsync(stats, 0, 512 * sizeof(float), stream);
  wcvt_kernel<<<64, 256, 0, stream>>>(wq, wk, wv, wo, Wh, Wl);
  attn_kernel<<<dim3(S_ / 16, B_), 64, 0, stream>>>(skip, dec, Wh, Wl, bq, bk, bv, bo,
                                                    ws_at, stats);
  gn_kernel<<<2048, 256, 0, stream>>>(ws_at, stats, gamma, beta, (float*)d_out);
}